// Round 14
// baseline (2564.639 us; speedup 1.0000x reference)
//
#include <hip/hip_runtime.h>
#include <hip/hip_bf16.h>
#include <math.h>

// ---------------- problem constants ----------------
// x: (4,512,50,50) f32; conv1_w: (512,512,3,3); heads: 36 loc + 18 score ch
// outputs (f32, concat): rpn_locs 360000 | rpn_scores 180000 @360000 |
//   rois 4800 @540000 | roi_indices 1200 @544800 | anchor 90000 @546000
//
// Numerics: proposal path f64 end-to-end (ref=np is f64).
// R14: heads reverted to DETERMINISTIC single-writer form (R11's f64
// atomicAdd accumulation made scores ulp-nondeterministic across launches ->
// rare rank flips -> R13's post-timing divergence). RULE: selection-critical
// scores must be bitwise deterministic. Conv keeps R12's 8-ic chunks
// (72 MFMA/barrier) with R13's correct init ordering.

typedef double f64x4 __attribute__((ext_vector_type(4)));

// ======================= conv 3x3 via f64 MFMA, 8-ic chunks, dbuf ===========
// block 256 thr = 4 waves; tile 64 oc x 50 px (1 row); grid (50,8,4).
// Per MFMA: A=W[16 oc][4 ic] (lane=16k+m), B=X[4 ic][16 px] (lane=16k+n).
__global__ __launch_bounds__(256) void conv3x3_kernel(
    const float* __restrict__ xg, const float* __restrict__ wg,
    const float* __restrict__ bg, double* __restrict__ featD)
{
  const int y0 = blockIdx.x, ocb = blockIdx.y, n = blockIdx.z;
  const int t = threadIdx.x;
  const int lane = t & 63;
  const int wv = t >> 6;          // wave id 0..3 -> oc group
  const int lm = lane & 15;       // m (A) / n (B) within tile
  const int kq = lane >> 4;       // k 0..3
  const int oc0 = ocb * 64;

  // ---- C/D layout probe: A[m][k]=m, B[k][n]=(k==0) -> D[m][n]=m exactly ----
  bool isM2;
  {
    f64x4 pr = (f64x4){0., 0., 0., 0.};
    double pa = (double)lm;
    double pb = (kq == 0) ? 1.0 : 0.0;
    pr = __builtin_amdgcn_mfma_f64_16x16x4f64(pa, pb, pr, 0, 0, 0);
    double v = __builtin_amdgcn_readfirstlane(pr[1]);  // lane0: M1->1, M2->4
    isM2 = (v > 2.5);
  }

  // sIn: [ic(8): stride 176][row(3): stride 56][x: 52]; slack zeroed.
  __shared__ float sIn[2][1424];
  // sW: [oc(64): stride 73][r = ic*9+tap (72)]; writes lane-consecutive
  // (conflict-free); reads one scalar/lane, <=2-way.
  __shared__ float sW[2][4672];

  for (int e = t; e < 2 * 1424; e += 256) ((float*)sIn)[e] = 0.f;
  __syncthreads();

  f64x4 acc[4];
  #pragma unroll
  for (int nt = 0; nt < 4; nt++) acc[nt] = (f64x4){0., 0., 0., 0.};

  int pbase[4];
  #pragma unroll
  for (int nt = 0; nt < 4; nt++) {
    int p = nt * 16 + lm;               // px; p>=50 lanes read slack, discarded
    pbase[nt] = kq * 176 + p;
  }

  float xr[5], wr18[18];
  // ---- load chunk 0 (ic 0..7) into registers ----
  #pragma unroll
  for (int k = 0; k < 5; k++) {
    int e = t + k * 256;
    float v = 0.f;
    if (e < 1248) {
      int ic = e / 156, rem = e - ic * 156;
      int r = rem / 52, xx = rem - r * 52;
      int yy = y0 + r - 1, xc = xx - 1;
      if (yy >= 0 && yy < 50 && xc >= 0 && xc < 50)
        v = xg[(((size_t)n * 512 + ic) * 50 + yy) * 50 + xc];
    }
    xr[k] = v;
  }
  #pragma unroll
  for (int k = 0; k < 18; k++) {
    int e = t + k * 256;
    int oc = e / 72, r = e - oc * 72;
    int ic = r / 9, tap = r - ic * 9;
    wr18[k] = wg[((size_t)(oc0 + oc) * 512 + ic) * 9 + tap];
  }
  // ---- store chunk 0 into buffer 0 ----
  #pragma unroll
  for (int k = 0; k < 5; k++) {
    int e = t + k * 256;
    if (e < 1248) {
      int ic = e / 156, rem = e - ic * 156;
      int r = rem / 52, xx = rem - r * 52;
      sIn[0][ic * 176 + r * 56 + xx] = xr[k];
    }
  }
  #pragma unroll
  for (int k = 0; k < 18; k++) {
    int e = t + k * 256;
    int oc = e / 72, r = e - oc * 72;
    sW[0][oc * 73 + r] = wr18[k];
  }

  const int ocl = wv * 16 + lm;
  for (int c = 0; c < 64; c++) {
    __syncthreads();                      // buf[c&1] ready for all waves
    const int cur = c & 1, nxt = cur ^ 1;
    const int ic0n = (c + 1) * 8;
    if (c + 1 < 64) {                     // issue global loads for chunk c+1
      #pragma unroll
      for (int k = 0; k < 5; k++) {
        int e = t + k * 256;
        float v = 0.f;
        if (e < 1248) {
          int ic = e / 156, rem = e - ic * 156;
          int r = rem / 52, xx = rem - r * 52;
          int yy = y0 + r - 1, xc = xx - 1;
          if (yy >= 0 && yy < 50 && xc >= 0 && xc < 50)
            v = xg[(((size_t)n * 512 + ic0n + ic) * 50 + yy) * 50 + xc];
        }
        xr[k] = v;
      }
      #pragma unroll
      for (int k = 0; k < 18; k++) {
        int e = t + k * 256;
        int oc = e / 72, r = e - oc * 72;
        int ic = r / 9, tap = r - ic * 9;
        wr18[k] = wg[((size_t)(oc0 + oc) * 512 + ic0n + ic) * 9 + tap];
      }
    }
    // ---- compute on buf[cur]: 9 taps x 2 ks x 4 nt = 72 MFMA ----
    #pragma unroll
    for (int tap = 0; tap < 9; tap++) {
      const int ky = tap / 3, kx = tap - ky * 3;
      const int off = ky * 56 + kx;
      #pragma unroll
      for (int ks = 0; ks < 2; ks++) {
        const double a = (double)sW[cur][ocl * 73 + (ks * 4 + kq) * 9 + tap];
        const int base = ks * 704 + off;
        #pragma unroll
        for (int nt = 0; nt < 4; nt++) {
          const double b = (double)sIn[cur][pbase[nt] + base];
          acc[nt] = __builtin_amdgcn_mfma_f64_16x16x4f64(a, b, acc[nt], 0, 0, 0);
        }
      }
    }
    // ---- store chunk c+1 into buf[nxt] ----
    if (c + 1 < 64) {
      #pragma unroll
      for (int k = 0; k < 5; k++) {
        int e = t + k * 256;
        if (e < 1248) {
          int ic = e / 156, rem = e - ic * 156;
          int r = rem / 52, xx = rem - r * 52;
          sIn[nxt][ic * 176 + r * 56 + xx] = xr[k];
        }
      }
      #pragma unroll
      for (int k = 0; k < 18; k++) {
        int e = t + k * 256;
        int oc = e / 72, r = e - oc * 72;
        sW[nxt][oc * 73 + r] = wr18[k];
      }
    }
  }

  // epilogue: bias + relu (f64); row mapping per probe
  #pragma unroll
  for (int nt = 0; nt < 4; nt++) {
    int p = nt * 16 + lm;
    if (p < 50) {
      #pragma unroll
      for (int i = 0; i < 4; i++) {
        int row = isM2 ? (kq + 4 * i) : (kq * 4 + i);
        int oc = oc0 + wv * 16 + row;
        featD[(((size_t)n * 512 + oc) * 50 + y0) * 50 + p] =
            fmax(acc[nt][i] + (double)bg[oc], 0.0);
      }
    }
  }
}

// ======================= 1x1 heads (loc 36 + score 18), f64, DETERMINISTIC ===
// one thread owns each (p, 8-oc) output; fixed 512-iteration sum; no atomics.
// weights staged in LDS (reads wave-uniform -> broadcast).
__global__ __launch_bounds__(256) void heads_kernel(
    const double* __restrict__ featD,
    const float* __restrict__ loc_w, const float* __restrict__ loc_b,
    const float* __restrict__ score_w, const float* __restrict__ score_b,
    double* __restrict__ locD, double* __restrict__ scoreD,
    float* __restrict__ out)
{
  const int p = blockIdx.x * 256 + threadIdx.x;
  const int ocg = blockIdx.y;
  const int n = blockIdx.z;
  const bool pv = (p < 2500);
  const int pp = pv ? p : 0;
  const double* fbase = featD + (size_t)n * 512 * 2500 + pp;

  __shared__ float wsh[8 * 512];
  double bias[8];
  #pragma unroll
  for (int jj = 0; jj < 8; jj++) {
    int oc = ocg * 8 + jj;
    int occ = (oc < 54) ? oc : 0;
    bias[jj] = (occ < 36) ? (double)loc_b[occ] : (double)score_b[occ - 36];
  }
  for (int e = threadIdx.x; e < 8 * 512; e += 256) {
    int jj = e >> 9, c = e & 511;
    int oc = ocg * 8 + jj;
    int occ = (oc < 54) ? oc : 0;
    wsh[e] = (occ < 36) ? loc_w[(size_t)occ * 512 + c]
                        : score_w[(size_t)(occ - 36) * 512 + c];
  }
  __syncthreads();

  double acc[8] = {0, 0, 0, 0, 0, 0, 0, 0};
  #pragma unroll 4
  for (int c = 0; c < 512; c++) {
    double f = fbase[(size_t)c * 2500];
    #pragma unroll
    for (int jj = 0; jj < 8; jj++) acc[jj] += f * (double)wsh[jj * 512 + c];
  }
  if (!pv) return;
  #pragma unroll
  for (int jj = 0; jj < 8; jj++) {
    int oc = ocg * 8 + jj;
    if (oc >= 54) break;
    double v = acc[jj] + bias[jj];
    if (oc < 36) {
      locD[(size_t)n * 90000 + (size_t)p * 36 + oc] = v;
      out[(size_t)n * 90000 + (size_t)p * 36 + oc] = (float)v;
    } else {
      scoreD[(size_t)n * 45000 + (size_t)p * 18 + (oc - 36)] = v;
      out[360000 + (size_t)n * 45000 + (size_t)p * 18 + (oc - 36)] = (float)v;
    }
  }
}

// robust scalar decode: harness may deliver python ints as int32 or float32
__device__ inline double decode_dim(const int* p) {
  int v = p[0];
  if (v > 0 && v < 1000000) return (double)v;
  return (double)__int_as_float(v);
}

// ======== zero hist/sValid/cnt — MUST run after heads (aliases featD) ========
__global__ void zero_kernel(unsigned* __restrict__ hist, int* __restrict__ sValid,
                            unsigned* __restrict__ cnt)
{
  const int i = blockIdx.x * 256 + threadIdx.x;
  if (i < 262144) hist[i] = 0u;
  if (i < 12000) sValid[i] = 0;
  if (i < 4) cnt[i] = 0u;
}

// ======================= anchors + loc2bbox + clip + valid + fg (f64) ========
__global__ void prep_kernel(const double* __restrict__ locD,
                            const double* __restrict__ scoreD,
                            const int* __restrict__ img_h_p, const int* __restrict__ img_w_p,
                            double* __restrict__ roiD, double* __restrict__ selD,
                            unsigned* __restrict__ hist, float* __restrict__ d_out)
{
  const int i = blockIdx.x * 256 + threadIdx.x;
  const int n = blockIdx.y;
  if (i >= 22500) return;
  const int p = i / 9, ab = i - p * 9;
  const int y = p / 50, x = p - y * 50;
  const int ri = ab / 3, sidx = ab - ri * 3;
  const double rr = (ri == 0) ? 0.5 : (ri == 1 ? 1.0 : 2.0);
  const double sc = (sidx == 0) ? 8.0 : (sidx == 1 ? 16.0 : 32.0);
  const double hh = 16.0 * sc * sqrt(rr);
  const double wd = 16.0 * sc * sqrt(1.0 / rr);
  const float bx1 = (float)(8.0 - wd * 0.5), by1 = (float)(8.0 - hh * 0.5);
  const float bx2 = (float)(8.0 + wd * 0.5), by2 = (float)(8.0 + hh * 0.5);
  const float sxf = (float)(x * 16), syf = (float)(y * 16);
  const float ax1 = bx1 + sxf, ay1 = by1 + syf, ax2 = bx2 + sxf, ay2 = by2 + syf;
  if (n == 0) {
    ((float4*)(d_out + 546000))[i] = make_float4(ax1, ay1, ax2, ay2);
  }
  const double l0 = locD[(size_t)n * 90000 + (size_t)i * 4 + 0];
  const double l1 = locD[(size_t)n * 90000 + (size_t)i * 4 + 1];
  const double l2 = locD[(size_t)n * 90000 + (size_t)i * 4 + 2];
  const double l3 = locD[(size_t)n * 90000 + (size_t)i * 4 + 3];
  const double s0 = scoreD[(size_t)n * 45000 + (size_t)i * 2 + 0];
  const double s1 = scoreD[(size_t)n * 45000 + (size_t)i * 2 + 1];
  const double aw = (double)ax2 - (double)ax1, ah = (double)ay2 - (double)ay1;
  const double acx = (double)ax1 + 0.5 * aw, acy = (double)ay1 + 0.5 * ah;
  const double cx = l0 * aw + acx, cy = l1 * ah + acy;
  const double ww = exp(l2) * aw, hh2 = exp(l3) * ah;
  double x1 = cx - 0.5 * ww, y1 = cy - 0.5 * hh2;
  double x2 = cx + 0.5 * ww, y2 = cy + 0.5 * hh2;
  const double fw = decode_dim(img_w_p), fh = decode_dim(img_h_p);
  x1 = fmin(fmax(x1, 0.0), fw); x2 = fmin(fmax(x2, 0.0), fw);
  y1 = fmin(fmax(y1, 0.0), fh); y2 = fmin(fmax(y2, 0.0), fh);
  const bool valid = (x2 - x1 + 1.0 >= 16.0) && (y2 - y1 + 1.0 >= 16.0);
  const double m = fmax(s0, s1);
  const double e0 = exp(s0 - m), e1 = exp(s1 - m);
  const double fg = e1 / (e0 + e1);
  double* rb = roiD + ((size_t)n * 22500 + i) * 4;
  rb[0] = x1; rb[1] = y1; rb[2] = x2; rb[3] = y2;
  selD[(size_t)n * 22500 + i] = valid ? fg : -INFINITY;
  if (valid) {  // fg in (0,1): positive f64 -> bits order == value order
    unsigned key = (unsigned)((unsigned long long)__double_as_longlong(fg) >> 48);
    atomicAdd(&hist[n * 65536 + key], 1u);  // integer atomic: order-independent
  }
}

// ======================= threshold: largest key class covering top-3000 ======
__global__ __launch_bounds__(256) void thresh_kernel(
    const unsigned* __restrict__ hist, unsigned* __restrict__ thrP)
{
  const int n = blockIdx.x;
  const int t = threadIdx.x;
  __shared__ unsigned csum[256];
  __shared__ unsigned hv[256];
  __shared__ int cstar;
  __shared__ unsigned sufS;
  const unsigned* h = hist + (size_t)n * 65536;
  unsigned s = 0;
  for (int k = 0; k < 256; k++) s += h[t * 256 + k];
  csum[t] = s;
  __syncthreads();
  if (t == 0) {
    unsigned suf = 0; int cs = -1;
    for (int c = 255; c >= 0; c--) {
      if (suf + csum[c] >= 3000u) { cs = c; break; }
      suf += csum[c];
    }
    cstar = cs; sufS = suf;
  }
  __syncthreads();
  const int cs = cstar;
  if (cs >= 0) hv[t] = h[cs * 256 + t];
  __syncthreads();
  if (t == 0) {
    unsigned Tkey = 0;
    if (cs >= 0) {
      unsigned suf = sufS;
      for (int v = 255; v >= 0; v--) {
        suf += hv[v];
        if (suf >= 3000u) { Tkey = (unsigned)(cs * 256 + v); break; }
      }
    }
    thrP[n] = Tkey;   // 0 if <3000 valid -> all valid become candidates
  }
}

// ======================= compact candidates (key >= threshold) ===============
// atomic order permutes candidate storage only; crank's output depends only
// on the SET + (score, index) -> deterministic.
__global__ void compact_kernel(const double* __restrict__ selD,
                               const unsigned* __restrict__ thrP,
                               unsigned* __restrict__ cnt,
                               int* __restrict__ candIdx, double* __restrict__ candS)
{
  const int i = blockIdx.x * 256 + threadIdx.x;
  const int n = blockIdx.y;
  if (i >= 22500) return;
  const double s = selD[(size_t)n * 22500 + i];
  if (!(s > -INFINITY)) return;
  unsigned key = (unsigned)((unsigned long long)__double_as_longlong(s) >> 48);
  if (key < thrP[n]) return;
  unsigned pos = atomicAdd(&cnt[n], 1u);
  candIdx[(size_t)n * 22500 + pos] = i;
  candS[(size_t)n * 22500 + pos] = s;
}

// ======================= exact rank among candidates (= lax.top_k order) =====
__global__ __launch_bounds__(256) void crank_kernel(
    const unsigned* __restrict__ cnt, const int* __restrict__ candIdx,
    const double* __restrict__ candS, const double* __restrict__ roiD,
    double* __restrict__ sBoxD, int* __restrict__ sValid)
{
  const int n = blockIdx.y;
  const int m = (int)cnt[n];
  if ((int)(blockIdx.x * 256) >= m) return;   // block-uniform early exit
  const int tid = blockIdx.x * 256 + threadIdx.x;
  const bool act = (tid < m);
  const double si = act ? candS[(size_t)n * 22500 + tid] : 0.0;
  const int ii = act ? candIdx[(size_t)n * 22500 + tid] : 0x7fffffff;
  __shared__ double sv[256];
  __shared__ int siv[256];
  int rank = 0;
  for (int j0 = 0; j0 < m; j0 += 256) {
    __syncthreads();
    const int jl = j0 + threadIdx.x;
    if (jl < m) {
      sv[threadIdx.x] = candS[(size_t)n * 22500 + jl];
      siv[threadIdx.x] = candIdx[(size_t)n * 22500 + jl];
    }
    __syncthreads();
    const int lim = (m - j0 < 256) ? (m - j0) : 256;
    for (int k = 0; k < lim; k++) {
      const double sj = sv[k];
      const int ij = siv[k];
      rank += ((sj > si) || (sj == si && ij < ii)) ? 1 : 0;
    }
  }
  if (act && rank < 3000) {
    const double* rb = roiD + ((size_t)n * 22500 + ii) * 4;
    double* db = sBoxD + ((size_t)n * 3000 + rank) * 4;
    db[0] = rb[0]; db[1] = rb[1]; db[2] = rb[2]; db[3] = rb[3];
    sValid[n * 3000 + rank] = 1;
  }
}

// ======================= NMS phase A: suppression bitmask (f64 IoU) ==========
__global__ void supmat_kernel(const double* __restrict__ sBoxD,
                              unsigned long long* __restrict__ sup)
{
  const int wj = blockIdx.x, ig = blockIdx.y, n = blockIdx.z;
  const int lane = threadIdx.x;
  const int i = ig * 64 + lane;
  if (wj < ig) {                       // strictly below diagonal: all zero
    if (i < 3000) sup[((size_t)n * 3000 + i) * 47 + wj] = 0ull;
    return;
  }
  __shared__ double jb[64][4];
  const int j0 = wj * 64;
  {
    int j = j0 + lane;
    if (j < 3000) {
      const double* b = sBoxD + ((size_t)n * 3000 + j) * 4;
      jb[lane][0] = b[0]; jb[lane][1] = b[1]; jb[lane][2] = b[2]; jb[lane][3] = b[3];
    } else {
      jb[lane][0] = 0; jb[lane][1] = 0; jb[lane][2] = 0; jb[lane][3] = 0;
    }
  }
  __syncthreads();
  if (i >= 3000) return;
  const double* bi = sBoxD + ((size_t)n * 3000 + i) * 4;
  const double bx1 = bi[0], by1 = bi[1], bx2 = bi[2], by2 = bi[3];
  const double ai = (bx2 - bx1) * (by2 - by1);
  unsigned long long msk = 0;
  #pragma unroll 2
  for (int tt = 0; tt < 64; tt++) {
    const int j = j0 + tt;
    const double jx1 = jb[tt][0], jy1 = jb[tt][1], jx2 = jb[tt][2], jy2 = jb[tt][3];
    double iw = fmax(fmin(bx2, jx2) - fmax(bx1, jx1), 0.0);
    double ih = fmax(fmin(by2, jy2) - fmax(by1, jy1), 0.0);
    double inter = iw * ih;
    double aj = (jx2 - jx1) * (jy2 - jy1);
    double iou = inter / (ai + aj - inter + 1e-9);
    if (iou > 0.7 && j > i && j < 3000) msk |= (1ull << tt);
  }
  sup[((size_t)n * 3000 + i) * 47 + wj] = msk;
}

// ======================= NMS phase B: scan + outputs =======================
#define SCAN_DEPTH 12   // 3000 = 12 * 250
__global__ void nms_scan_kernel(const double* __restrict__ sBoxD,
                                const int* __restrict__ sValid,
                                const unsigned long long* __restrict__ sup,
                                float* __restrict__ out)
{
  const int n = blockIdx.x;
  const int lane = threadIdx.x;
  unsigned long long alive = 0;
  for (int w = 0; w < 47; w++) {
    int idx = w * 64 + lane;
    int v = (idx < 3000) ? sValid[(size_t)n * 3000 + idx] : 0;
    unsigned long long bm = __ballot(v != 0);
    if (lane == w) alive = bm;
  }
  const unsigned long long* srow = sup + (size_t)n * 3000 * 47;
  const bool ld = (lane < 47);
  unsigned long long buf[SCAN_DEPTH];
  #pragma unroll
  for (int d = 0; d < SCAN_DEPTH; d++)
    buf[d] = ld ? srow[(size_t)d * 47 + lane] : 0ull;
  for (int ib = 0; ib < 3000; ib += SCAN_DEPTH) {
    #pragma unroll
    for (int d = 0; d < SCAN_DEPTH; d++) {
      const int i = ib + d;
      const unsigned long long row = buf[d];
      const int pf = i + SCAN_DEPTH;
      buf[d] = (ld && pf < 3000) ? srow[(size_t)pf * 47 + lane] : 0ull;
      const unsigned long long aw = __shfl(alive, i >> 6);
      if ((aw >> (i & 63)) & 1ull) alive &= ~row;
    }
  }
  int c = __popcll(alive);
  int pre = c;
  #pragma unroll
  for (int off = 1; off < 64; off <<= 1) {
    int t2 = __shfl_up(pre, off);
    if (lane >= off) pre += t2;
  }
  const int excl = pre - c;
  const int tot = __shfl(pre, 63);
  float4* rois4 = (float4*)(out + 540000);
  unsigned long long a = alive;
  int r = excl;
  while (a) {
    int b = __ffsll((unsigned long long)a) - 1;
    a &= (a - 1);
    if (r < 300) {
      int i = lane * 64 + b;
      const double* bb = sBoxD + ((size_t)n * 3000 + i) * 4;
      rois4[n * 300 + r] = make_float4((float)bb[0], (float)bb[1],
                                       (float)bb[2], (float)bb[3]);
    }
    r++;
  }
  for (int k = tot + lane; k < 300; k += 64)
    rois4[n * 300 + k] = make_float4(0, 0, 0, 0);
  for (int k = lane; k < 300; k += 64)
    out[544800 + n * 300 + k] = (float)n;
}

// ======================= launch =======================
extern "C" void kernel_launch(void* const* d_in, const int* in_sizes, int n_in,
                              void* d_out, int out_size, void* d_ws, size_t ws_size,
                              hipStream_t stream) {
  const float* x        = (const float*)d_in[0];
  const float* conv1_w  = (const float*)d_in[1];
  const float* conv1_b  = (const float*)d_in[2];
  const float* loc_w    = (const float*)d_in[3];
  const float* loc_b    = (const float*)d_in[4];
  const float* score_w  = (const float*)d_in[5];
  const float* score_b  = (const float*)d_in[6];
  const int*   img_h    = (const int*)d_in[7];
  const int*   img_w    = (const int*)d_in[8];
  float* out = (float*)d_out;
  char* ws = (char*)d_ws;

  // live ranges: featD conv->heads only; then its region is recycled.
  double* featD  = (double*)(ws);                  // [0, 40,960,000)
  double* locD   = (double*)(ws + 40960000);       // +2,880,000
  double* scoreD = (double*)(ws + 43840000);       // +1,440,000 -> 45,280,000
  // aliases into featD's dead region (all used strictly after heads_kernel):
  double* roiD   = (double*)(ws);                  // [0, 2,880,000)
  double* selD   = (double*)(ws + 2880000);        // +720,000
  double* sBoxD  = (double*)(ws + 3600000);        // +384,000
  int*    sValid = (int*)(ws + 4000000);           // +48,000
  unsigned long long* sup = (unsigned long long*)(ws + 4100000);  // +4,512,000
  unsigned* hist   = (unsigned*)(ws + 8700000);    // +1,048,576
  unsigned* cnt    = (unsigned*)(ws + 9750000);    // +16
  unsigned* thrP   = (unsigned*)(ws + 9751040);    // +16
  int*      candIdx= (int*)(ws + 9752000);         // +360,000
  double*   candS  = (double*)(ws + 10200000);     // +720,000 -> 10,920,000

  conv3x3_kernel<<<dim3(50, 8, 4), 256, 0, stream>>>(x, conv1_w, conv1_b, featD);
  heads_kernel<<<dim3(10, 7, 4), 256, 0, stream>>>(featD, loc_w, loc_b, score_w, score_b,
                                                   locD, scoreD, out);
  zero_kernel<<<1024, 256, 0, stream>>>(hist, sValid, cnt);   // after heads!
  prep_kernel<<<dim3(88, 4), 256, 0, stream>>>(locD, scoreD, img_h, img_w,
                                               roiD, selD, hist, out);
  thresh_kernel<<<4, 256, 0, stream>>>(hist, thrP);
  compact_kernel<<<dim3(88, 4), 256, 0, stream>>>(selD, thrP, cnt, candIdx, candS);
  crank_kernel<<<dim3(88, 4), 256, 0, stream>>>(cnt, candIdx, candS, roiD, sBoxD, sValid);
  supmat_kernel<<<dim3(47, 47, 4), 64, 0, stream>>>(sBoxD, sup);
  nms_scan_kernel<<<4, 64, 0, stream>>>(sBoxD, sValid, sup, out);
}

// Round 16
// 2409.484 us; speedup vs baseline: 1.0644x; 1.0644x over previous
//
#include <hip/hip_runtime.h>
#include <hip/hip_bf16.h>
#include <math.h>

// ---------------- problem constants ----------------
// x: (4,512,50,50) f32; conv1_w: (512,512,3,3); heads: 36 loc + 18 score ch
// outputs (f32, concat): rpn_locs 360000 | rpn_scores 180000 @360000 |
//   rois 4800 @540000 | roi_indices 1200 @544800 | anchor 90000 @546000
//
// Numerics: proposal path f64 end-to-end (ref=np is f64).
// R16: pipeline made BITWISE DETERMINISTIC end-to-end: atomic compaction
// replaced by 2-phase deterministic compaction (ballot count -> serial scan
// -> index-ordered scatter); sBoxD pre-zeroed. R13/R15 post-timing failures
// showed launch-over-launch divergence; the only nondet ordering left was
// compact's atomicAdd — now gone. Conv = R11's (best measured: 1305us).

typedef double f64x4 __attribute__((ext_vector_type(4)));

// ======================= conv 3x3 via f64 MFMA, 4-ic chunks, dbuf ===========
// block 256 thr = 4 waves; tile 64 oc x 50 px (1 row); grid (50,8,4).
__global__ __launch_bounds__(256) void conv3x3_kernel(
    const float* __restrict__ xg, const float* __restrict__ wg,
    const float* __restrict__ bg, double* __restrict__ featD)
{
  const int y0 = blockIdx.x, ocb = blockIdx.y, n = blockIdx.z;
  const int t = threadIdx.x;
  const int lane = t & 63;
  const int wv = t >> 6;          // wave id 0..3 -> oc group
  const int lm = lane & 15;       // m (A) / n (B) within tile
  const int kq = lane >> 4;       // k 0..3
  const int oc0 = ocb * 64;

  // ---- C/D layout probe: A[m][k]=m, B[k][n]=(k==0) -> D[m][n]=m exactly ----
  bool isM2;
  {
    f64x4 pr = (f64x4){0., 0., 0., 0.};
    double pa = (double)lm;
    double pb = (kq == 0) ? 1.0 : 0.0;
    pr = __builtin_amdgcn_mfma_f64_16x16x4f64(pa, pb, pr, 0, 0, 0);
    double v = __builtin_amdgcn_readfirstlane(pr[1]);  // lane0: M1->1, M2->4
    isM2 = (v > 2.5);
  }

  __shared__ float sIn[2][720];    // [ic:176][row(3):56][x:52], slack zeroed
  __shared__ float sW[2][2368];    // [oc:37][tap*4+ic], writes lane-consecutive

  for (int e = t; e < 2 * 720; e += 256) ((float*)sIn)[e] = 0.f;
  __syncthreads();

  f64x4 acc[4];
  #pragma unroll
  for (int nt = 0; nt < 4; nt++) acc[nt] = (f64x4){0., 0., 0., 0.};

  int pbase[4];
  #pragma unroll
  for (int nt = 0; nt < 4; nt++) {
    int p = nt * 16 + lm;
    pbase[nt] = kq * 176 + p;
  }

  float xr[3], wr9[9];
  #pragma unroll
  for (int k = 0; k < 3; k++) {
    int e = t + k * 256;
    float v = 0.f;
    if (e < 624) {
      int ic = e / 156, rem = e - ic * 156;
      int r = rem / 52, xx = rem - r * 52;
      int yy = y0 + r - 1, xc = xx - 1;
      if (yy >= 0 && yy < 50 && xc >= 0 && xc < 50)
        v = xg[(((size_t)n * 512 + ic) * 50 + yy) * 50 + xc];
    }
    xr[k] = v;
  }
  #pragma unroll
  for (int k = 0; k < 9; k++) {
    int e = t + k * 256;
    int oc = e / 36, rem = e - oc * 36;
    int ic = rem / 9, tap = rem - ic * 9;
    wr9[k] = wg[((size_t)(oc0 + oc) * 512 + ic) * 9 + tap];
  }
  #pragma unroll
  for (int k = 0; k < 3; k++) {
    int e = t + k * 256;
    if (e < 624) {
      int ic = e / 156, rem = e - ic * 156;
      int r = rem / 52, xx = rem - r * 52;
      sIn[0][ic * 176 + r * 56 + xx] = xr[k];
    }
  }
  #pragma unroll
  for (int k = 0; k < 9; k++) {
    int e = t + k * 256;
    int oc = e / 36, rem = e - oc * 36;
    int ic = rem / 9, tap = rem - ic * 9;
    sW[0][oc * 37 + tap * 4 + ic] = wr9[k];
  }

  for (int c = 0; c < 128; c++) {
    __syncthreads();
    const int cur = c & 1, nxt = cur ^ 1;
    const int ic0n = (c + 1) * 4;
    if (c + 1 < 128) {
      #pragma unroll
      for (int k = 0; k < 3; k++) {
        int e = t + k * 256;
        float v = 0.f;
        if (e < 624) {
          int ic = e / 156, rem = e - ic * 156;
          int r = rem / 52, xx = rem - r * 52;
          int yy = y0 + r - 1, xc = xx - 1;
          if (yy >= 0 && yy < 50 && xc >= 0 && xc < 50)
            v = xg[(((size_t)n * 512 + ic0n + ic) * 50 + yy) * 50 + xc];
        }
        xr[k] = v;
      }
      #pragma unroll
      for (int k = 0; k < 9; k++) {
        int e = t + k * 256;
        int oc = e / 36, rem = e - oc * 36;
        int ic = rem / 9, tap = rem - ic * 9;
        wr9[k] = wg[((size_t)(oc0 + oc) * 512 + ic0n + ic) * 9 + tap];
      }
    }
    #pragma unroll
    for (int tap = 0; tap < 9; tap++) {
      const int ky = tap / 3, kx = tap - ky * 3;
      const double a = (double)sW[cur][(wv * 16 + lm) * 37 + tap * 4 + kq];
      const int off = ky * 56 + kx;
      #pragma unroll
      for (int nt = 0; nt < 4; nt++) {
        const double b = (double)sIn[cur][pbase[nt] + off];
        acc[nt] = __builtin_amdgcn_mfma_f64_16x16x4f64(a, b, acc[nt], 0, 0, 0);
      }
    }
    if (c + 1 < 128) {
      #pragma unroll
      for (int k = 0; k < 3; k++) {
        int e = t + k * 256;
        if (e < 624) {
          int ic = e / 156, rem = e - ic * 156;
          int r = rem / 52, xx = rem - r * 52;
          sIn[nxt][ic * 176 + r * 56 + xx] = xr[k];
        }
      }
      #pragma unroll
      for (int k = 0; k < 9; k++) {
        int e = t + k * 256;
        int oc = e / 36, rem = e - oc * 36;
        int ic = rem / 9, tap = rem - ic * 9;
        sW[nxt][oc * 37 + tap * 4 + ic] = wr9[k];
      }
    }
  }

  #pragma unroll
  for (int nt = 0; nt < 4; nt++) {
    int p = nt * 16 + lm;
    if (p < 50) {
      #pragma unroll
      for (int i = 0; i < 4; i++) {
        int row = isM2 ? (kq + 4 * i) : (kq * 4 + i);
        int oc = oc0 + wv * 16 + row;
        featD[(((size_t)n * 512 + oc) * 50 + y0) * 50 + p] =
            fmax(acc[nt][i] + (double)bg[oc], 0.0);
      }
    }
  }
}

// ======================= 1x1 heads (loc 36 + score 18), f64, DETERMINISTIC ===
__global__ __launch_bounds__(256) void heads_kernel(
    const double* __restrict__ featD,
    const float* __restrict__ loc_w, const float* __restrict__ loc_b,
    const float* __restrict__ score_w, const float* __restrict__ score_b,
    double* __restrict__ locD, double* __restrict__ scoreD,
    float* __restrict__ out)
{
  const int p = blockIdx.x * 256 + threadIdx.x;
  const int ocg = blockIdx.y;
  const int n = blockIdx.z;
  const bool pv = (p < 2500);
  const int pp = pv ? p : 0;
  const double* fbase = featD + (size_t)n * 512 * 2500 + pp;

  __shared__ float wsh[8 * 512];
  double bias[8];
  #pragma unroll
  for (int jj = 0; jj < 8; jj++) {
    int oc = ocg * 8 + jj;
    int occ = (oc < 54) ? oc : 0;
    bias[jj] = (occ < 36) ? (double)loc_b[occ] : (double)score_b[occ - 36];
  }
  for (int e = threadIdx.x; e < 8 * 512; e += 256) {
    int jj = e >> 9, c = e & 511;
    int oc = ocg * 8 + jj;
    int occ = (oc < 54) ? oc : 0;
    wsh[e] = (occ < 36) ? loc_w[(size_t)occ * 512 + c]
                        : score_w[(size_t)(occ - 36) * 512 + c];
  }
  __syncthreads();

  double acc[8] = {0, 0, 0, 0, 0, 0, 0, 0};
  #pragma unroll 4
  for (int c = 0; c < 512; c++) {
    double f = fbase[(size_t)c * 2500];
    #pragma unroll
    for (int jj = 0; jj < 8; jj++) acc[jj] += f * (double)wsh[jj * 512 + c];
  }
  if (!pv) return;
  #pragma unroll
  for (int jj = 0; jj < 8; jj++) {
    int oc = ocg * 8 + jj;
    if (oc >= 54) break;
    double v = acc[jj] + bias[jj];
    if (oc < 36) {
      locD[(size_t)n * 90000 + (size_t)p * 36 + oc] = v;
      out[(size_t)n * 90000 + (size_t)p * 36 + oc] = (float)v;
    } else {
      scoreD[(size_t)n * 45000 + (size_t)p * 18 + (oc - 36)] = v;
      out[360000 + (size_t)n * 45000 + (size_t)p * 18 + (oc - 36)] = (float)v;
    }
  }
}

// robust scalar decode: harness may deliver python ints as int32 or float32
__device__ inline double decode_dim(const int* p) {
  int v = p[0];
  if (v > 0 && v < 1000000) return (double)v;
  return (double)__int_as_float(v);
}

// ======== zero hist/sValid/sBoxD — MUST run after heads (aliases featD) ======
__global__ void zero_kernel(unsigned* __restrict__ hist, int* __restrict__ sValid,
                            double* __restrict__ sBoxD)
{
  const int i = blockIdx.x * 256 + threadIdx.x;
  if (i < 262144) hist[i] = 0u;
  if (i < 12000) sValid[i] = 0;
  if (i < 48000) sBoxD[i] = 0.0;
}

// ======================= anchors + loc2bbox + clip + valid + fg (f64) ========
__global__ void prep_kernel(const double* __restrict__ locD,
                            const double* __restrict__ scoreD,
                            const int* __restrict__ img_h_p, const int* __restrict__ img_w_p,
                            double* __restrict__ roiD, double* __restrict__ selD,
                            unsigned* __restrict__ hist, float* __restrict__ d_out)
{
  const int i = blockIdx.x * 256 + threadIdx.x;
  const int n = blockIdx.y;
  if (i >= 22500) return;
  const int p = i / 9, ab = i - p * 9;
  const int y = p / 50, x = p - y * 50;
  const int ri = ab / 3, sidx = ab - ri * 3;
  const double rr = (ri == 0) ? 0.5 : (ri == 1 ? 1.0 : 2.0);
  const double sc = (sidx == 0) ? 8.0 : (sidx == 1 ? 16.0 : 32.0);
  const double hh = 16.0 * sc * sqrt(rr);
  const double wd = 16.0 * sc * sqrt(1.0 / rr);
  const float bx1 = (float)(8.0 - wd * 0.5), by1 = (float)(8.0 - hh * 0.5);
  const float bx2 = (float)(8.0 + wd * 0.5), by2 = (float)(8.0 + hh * 0.5);
  const float sxf = (float)(x * 16), syf = (float)(y * 16);
  const float ax1 = bx1 + sxf, ay1 = by1 + syf, ax2 = bx2 + sxf, ay2 = by2 + syf;
  if (n == 0) {
    ((float4*)(d_out + 546000))[i] = make_float4(ax1, ay1, ax2, ay2);
  }
  const double l0 = locD[(size_t)n * 90000 + (size_t)i * 4 + 0];
  const double l1 = locD[(size_t)n * 90000 + (size_t)i * 4 + 1];
  const double l2 = locD[(size_t)n * 90000 + (size_t)i * 4 + 2];
  const double l3 = locD[(size_t)n * 90000 + (size_t)i * 4 + 3];
  const double s0 = scoreD[(size_t)n * 45000 + (size_t)i * 2 + 0];
  const double s1 = scoreD[(size_t)n * 45000 + (size_t)i * 2 + 1];
  const double aw = (double)ax2 - (double)ax1, ah = (double)ay2 - (double)ay1;
  const double acx = (double)ax1 + 0.5 * aw, acy = (double)ay1 + 0.5 * ah;
  const double cx = l0 * aw + acx, cy = l1 * ah + acy;
  const double ww = exp(l2) * aw, hh2 = exp(l3) * ah;
  double x1 = cx - 0.5 * ww, y1 = cy - 0.5 * hh2;
  double x2 = cx + 0.5 * ww, y2 = cy + 0.5 * hh2;
  const double fw = decode_dim(img_w_p), fh = decode_dim(img_h_p);
  x1 = fmin(fmax(x1, 0.0), fw); x2 = fmin(fmax(x2, 0.0), fw);
  y1 = fmin(fmax(y1, 0.0), fh); y2 = fmin(fmax(y2, 0.0), fh);
  const bool valid = (x2 - x1 + 1.0 >= 16.0) && (y2 - y1 + 1.0 >= 16.0);
  const double m = fmax(s0, s1);
  const double e0 = exp(s0 - m), e1 = exp(s1 - m);
  const double fg = e1 / (e0 + e1);
  double* rb = roiD + ((size_t)n * 22500 + i) * 4;
  rb[0] = x1; rb[1] = y1; rb[2] = x2; rb[3] = y2;
  selD[(size_t)n * 22500 + i] = valid ? fg : -INFINITY;
  if (valid) {  // fg in (0,1): positive f64 -> bits order == value order
    unsigned key = (unsigned)((unsigned long long)__double_as_longlong(fg) >> 48);
    atomicAdd(&hist[n * 65536 + key], 1u);  // integer atomic: order-independent
  }
}

// ======================= threshold: largest key class covering top-3000 ======
__global__ __launch_bounds__(256) void thresh_kernel(
    const unsigned* __restrict__ hist, unsigned* __restrict__ thrP)
{
  const int n = blockIdx.x;
  const int t = threadIdx.x;
  __shared__ unsigned csum[256];
  __shared__ unsigned hv[256];
  __shared__ int cstar;
  __shared__ unsigned sufS;
  const unsigned* h = hist + (size_t)n * 65536;
  unsigned s = 0;
  for (int k = 0; k < 256; k++) s += h[t * 256 + k];
  csum[t] = s;
  __syncthreads();
  if (t == 0) {
    unsigned suf = 0; int cs = -1;
    for (int c = 255; c >= 0; c--) {
      if (suf + csum[c] >= 3000u) { cs = c; break; }
      suf += csum[c];
    }
    cstar = cs; sufS = suf;
  }
  __syncthreads();
  const int cs = cstar;
  if (cs >= 0) hv[t] = h[cs * 256 + t];
  __syncthreads();
  if (t == 0) {
    unsigned Tkey = 0;
    if (cs >= 0) {
      unsigned suf = sufS;
      for (int v = 255; v >= 0; v--) {
        suf += hv[v];
        if (suf >= 3000u) { Tkey = (unsigned)(cs * 256 + v); break; }
      }
    }
    thrP[n] = Tkey;   // 0 if <3000 valid -> all valid become candidates
  }
}

// ============ deterministic 2-phase compaction (no atomics) =================
__device__ inline bool cand_flag(const double* __restrict__ selD,
                                 const unsigned* __restrict__ thrP,
                                 int n, int i, double* sOut) {
  double s = selD[(size_t)n * 22500 + i];
  *sOut = s;
  if (!(s > -INFINITY)) return false;
  unsigned key = (unsigned)((unsigned long long)__double_as_longlong(s) >> 48);
  return key >= thrP[n];
}

// phase 1: per-block candidate counts
__global__ __launch_bounds__(256) void ccount_kernel(
    const double* __restrict__ selD, const unsigned* __restrict__ thrP,
    unsigned* __restrict__ blkCnt)
{
  const int i = blockIdx.x * 256 + threadIdx.x;
  const int n = blockIdx.y;
  double s;
  bool f = (i < 22500) && cand_flag(selD, thrP, n, i, &s);
  unsigned long long b = __ballot(f);
  __shared__ unsigned wc[4];
  const int wv = threadIdx.x >> 6, lane = threadIdx.x & 63;
  if (lane == 0) wc[wv] = (unsigned)__popcll(b);
  __syncthreads();
  if (threadIdx.x == 0)
    blkCnt[n * 88 + blockIdx.x] = wc[0] + wc[1] + wc[2] + wc[3];
}

// phase 2: serial exclusive scan per n (88 entries; 4 lanes)
__global__ void cscan_kernel(const unsigned* __restrict__ blkCnt,
                             unsigned* __restrict__ blkOff,
                             unsigned* __restrict__ mOut)
{
  const int n = threadIdx.x;
  if (n >= 4) return;
  unsigned acc = 0;
  for (int b = 0; b < 88; b++) {
    blkOff[n * 88 + b] = acc;
    acc += blkCnt[n * 88 + b];
  }
  mOut[n] = acc;
}

// phase 3: index-ordered scatter at deterministic offsets
__global__ __launch_bounds__(256) void cscatter_kernel(
    const double* __restrict__ selD, const unsigned* __restrict__ thrP,
    const unsigned* __restrict__ blkOff,
    int* __restrict__ candIdx, double* __restrict__ candS)
{
  const int i = blockIdx.x * 256 + threadIdx.x;
  const int n = blockIdx.y;
  double s = 0.0;
  bool f = (i < 22500) && cand_flag(selD, thrP, n, i, &s);
  unsigned long long b = __ballot(f);
  const int wv = threadIdx.x >> 6, lane = threadIdx.x & 63;
  __shared__ unsigned wc[4];
  if (lane == 0) wc[wv] = (unsigned)__popcll(b);
  __syncthreads();
  unsigned woff = 0;
  for (int w = 0; w < wv; w++) woff += wc[w];
  unsigned lpre = (unsigned)__popcll(b & ((1ull << lane) - 1ull));
  if (f) {
    unsigned pos = blkOff[n * 88 + blockIdx.x] + woff + lpre;
    candIdx[(size_t)n * 22500 + pos] = i;
    candS[(size_t)n * 22500 + pos] = s;
  }
}

// ======================= exact rank among candidates (= lax.top_k order) =====
__global__ __launch_bounds__(256) void crank_kernel(
    const unsigned* __restrict__ mOut, const int* __restrict__ candIdx,
    const double* __restrict__ candS, const double* __restrict__ roiD,
    double* __restrict__ sBoxD, int* __restrict__ sValid)
{
  const int n = blockIdx.y;
  const int m = (int)mOut[n];
  if ((int)(blockIdx.x * 256) >= m) return;   // block-uniform early exit
  const int tid = blockIdx.x * 256 + threadIdx.x;
  const bool act = (tid < m);
  const double si = act ? candS[(size_t)n * 22500 + tid] : 0.0;
  const int ii = act ? candIdx[(size_t)n * 22500 + tid] : 0x7fffffff;
  __shared__ double sv[256];
  __shared__ int siv[256];
  int rank = 0;
  for (int j0 = 0; j0 < m; j0 += 256) {
    __syncthreads();
    const int jl = j0 + threadIdx.x;
    if (jl < m) {
      sv[threadIdx.x] = candS[(size_t)n * 22500 + jl];
      siv[threadIdx.x] = candIdx[(size_t)n * 22500 + jl];
    }
    __syncthreads();
    const int lim = (m - j0 < 256) ? (m - j0) : 256;
    for (int k = 0; k < lim; k++) {
      const double sj = sv[k];
      const int ij = siv[k];
      rank += ((sj > si) || (sj == si && ij < ii)) ? 1 : 0;
    }
  }
  if (act && rank < 3000) {
    const double* rb = roiD + ((size_t)n * 22500 + ii) * 4;
    double* db = sBoxD + ((size_t)n * 3000 + rank) * 4;
    db[0] = rb[0]; db[1] = rb[1]; db[2] = rb[2]; db[3] = rb[3];
    sValid[n * 3000 + rank] = 1;
  }
}

// ======================= NMS phase A: suppression bitmask (f64 IoU) ==========
__global__ void supmat_kernel(const double* __restrict__ sBoxD,
                              unsigned long long* __restrict__ sup)
{
  const int wj = blockIdx.x, ig = blockIdx.y, n = blockIdx.z;
  const int lane = threadIdx.x;
  const int i = ig * 64 + lane;
  if (wj < ig) {                       // strictly below diagonal: all zero
    if (i < 3000) sup[((size_t)n * 3000 + i) * 47 + wj] = 0ull;
    return;
  }
  __shared__ double jb[64][4];
  const int j0 = wj * 64;
  {
    int j = j0 + lane;
    if (j < 3000) {
      const double* b = sBoxD + ((size_t)n * 3000 + j) * 4;
      jb[lane][0] = b[0]; jb[lane][1] = b[1]; jb[lane][2] = b[2]; jb[lane][3] = b[3];
    } else {
      jb[lane][0] = 0; jb[lane][1] = 0; jb[lane][2] = 0; jb[lane][3] = 0;
    }
  }
  __syncthreads();
  if (i >= 3000) return;
  const double* bi = sBoxD + ((size_t)n * 3000 + i) * 4;
  const double bx1 = bi[0], by1 = bi[1], bx2 = bi[2], by2 = bi[3];
  const double ai = (bx2 - bx1) * (by2 - by1);
  unsigned long long msk = 0;
  #pragma unroll 2
  for (int tt = 0; tt < 64; tt++) {
    const int j = j0 + tt;
    const double jx1 = jb[tt][0], jy1 = jb[tt][1], jx2 = jb[tt][2], jy2 = jb[tt][3];
    double iw = fmax(fmin(bx2, jx2) - fmax(bx1, jx1), 0.0);
    double ih = fmax(fmin(by2, jy2) - fmax(by1, jy1), 0.0);
    double inter = iw * ih;
    double aj = (jx2 - jx1) * (jy2 - jy1);
    double iou = inter / (ai + aj - inter + 1e-9);
    if (iou > 0.7 && j > i && j < 3000) msk |= (1ull << tt);
  }
  sup[((size_t)n * 3000 + i) * 47 + wj] = msk;
}

// ======================= NMS phase B: scan + outputs =======================
#define SCAN_DEPTH 12   // 3000 = 12 * 250
__global__ void nms_scan_kernel(const double* __restrict__ sBoxD,
                                const int* __restrict__ sValid,
                                const unsigned long long* __restrict__ sup,
                                float* __restrict__ out)
{
  const int n = blockIdx.x;
  const int lane = threadIdx.x;
  unsigned long long alive = 0;
  for (int w = 0; w < 47; w++) {
    int idx = w * 64 + lane;
    int v = (idx < 3000) ? sValid[(size_t)n * 3000 + idx] : 0;
    unsigned long long bm = __ballot(v != 0);
    if (lane == w) alive = bm;
  }
  const unsigned long long* srow = sup + (size_t)n * 3000 * 47;
  const bool ld = (lane < 47);
  unsigned long long buf[SCAN_DEPTH];
  #pragma unroll
  for (int d = 0; d < SCAN_DEPTH; d++)
    buf[d] = ld ? srow[(size_t)d * 47 + lane] : 0ull;
  for (int ib = 0; ib < 3000; ib += SCAN_DEPTH) {
    #pragma unroll
    for (int d = 0; d < SCAN_DEPTH; d++) {
      const int i = ib + d;
      const unsigned long long row = buf[d];
      const int pf = i + SCAN_DEPTH;
      buf[d] = (ld && pf < 3000) ? srow[(size_t)pf * 47 + lane] : 0ull;
      const unsigned long long aw = __shfl(alive, i >> 6);
      if ((aw >> (i & 63)) & 1ull) alive &= ~row;
    }
  }
  int c = __popcll(alive);
  int pre = c;
  #pragma unroll
  for (int off = 1; off < 64; off <<= 1) {
    int t2 = __shfl_up(pre, off);
    if (lane >= off) pre += t2;
  }
  const int excl = pre - c;
  const int tot = __shfl(pre, 63);
  float4* rois4 = (float4*)(out + 540000);
  unsigned long long a = alive;
  int r = excl;
  while (a) {
    int b = __ffsll((unsigned long long)a) - 1;
    a &= (a - 1);
    if (r < 300) {
      int i = lane * 64 + b;
      const double* bb = sBoxD + ((size_t)n * 3000 + i) * 4;
      rois4[n * 300 + r] = make_float4((float)bb[0], (float)bb[1],
                                       (float)bb[2], (float)bb[3]);
    }
    r++;
  }
  for (int k = tot + lane; k < 300; k += 64)
    rois4[n * 300 + k] = make_float4(0, 0, 0, 0);
  for (int k = lane; k < 300; k += 64)
    out[544800 + n * 300 + k] = (float)n;
}

// ======================= launch =======================
extern "C" void kernel_launch(void* const* d_in, const int* in_sizes, int n_in,
                              void* d_out, int out_size, void* d_ws, size_t ws_size,
                              hipStream_t stream) {
  const float* x        = (const float*)d_in[0];
  const float* conv1_w  = (const float*)d_in[1];
  const float* conv1_b  = (const float*)d_in[2];
  const float* loc_w    = (const float*)d_in[3];
  const float* loc_b    = (const float*)d_in[4];
  const float* score_w  = (const float*)d_in[5];
  const float* score_b  = (const float*)d_in[6];
  const int*   img_h    = (const int*)d_in[7];
  const int*   img_w    = (const int*)d_in[8];
  float* out = (float*)d_out;
  char* ws = (char*)d_ws;

  // live ranges: featD conv->heads only; then its region is recycled.
  double* featD  = (double*)(ws);                  // [0, 40,960,000)
  double* locD   = (double*)(ws + 40960000);       // +2,880,000
  double* scoreD = (double*)(ws + 43840000);       // +1,440,000 -> 45,280,000
  // aliases into featD's dead region (all used strictly after heads_kernel):
  double* roiD   = (double*)(ws);                  // [0, 2,880,000)
  double* selD   = (double*)(ws + 2880000);        // +720,000
  double* sBoxD  = (double*)(ws + 3600000);        // +384,000
  int*    sValid = (int*)(ws + 4000000);           // +48,000
  unsigned long long* sup = (unsigned long long*)(ws + 4100000);  // +4,512,000
  unsigned* hist   = (unsigned*)(ws + 8700000);    // +1,048,576
  unsigned* blkCnt = (unsigned*)(ws + 9750000);    // +1,408
  unsigned* blkOff = (unsigned*)(ws + 9752000);    // +1,408
  unsigned* mOut   = (unsigned*)(ws + 9754000);    // +16
  unsigned* thrP   = (unsigned*)(ws + 9755000);    // +16
  int*      candIdx= (int*)(ws + 9760000);         // +360,000
  double*   candS  = (double*)(ws + 10200000);     // +720,000 -> 10,920,000

  conv3x3_kernel<<<dim3(50, 8, 4), 256, 0, stream>>>(x, conv1_w, conv1_b, featD);
  heads_kernel<<<dim3(10, 7, 4), 256, 0, stream>>>(featD, loc_w, loc_b, score_w, score_b,
                                                   locD, scoreD, out);
  zero_kernel<<<1024, 256, 0, stream>>>(hist, sValid, sBoxD);   // after heads!
  prep_kernel<<<dim3(88, 4), 256, 0, stream>>>(locD, scoreD, img_h, img_w,
                                               roiD, selD, hist, out);
  thresh_kernel<<<4, 256, 0, stream>>>(hist, thrP);
  ccount_kernel<<<dim3(88, 4), 256, 0, stream>>>(selD, thrP, blkCnt);
  cscan_kernel<<<1, 64, 0, stream>>>(blkCnt, blkOff, mOut);
  cscatter_kernel<<<dim3(88, 4), 256, 0, stream>>>(selD, thrP, blkOff, candIdx, candS);
  crank_kernel<<<dim3(88, 4), 256, 0, stream>>>(mOut, candIdx, candS, roiD, sBoxD, sValid);
  supmat_kernel<<<dim3(47, 47, 4), 64, 0, stream>>>(sBoxD, sup);
  nms_scan_kernel<<<4, 64, 0, stream>>>(sBoxD, sValid, sup, out);
}